// Round 1
// baseline (220.087 us; speedup 1.0000x reference)
//
#include <hip/hip_runtime.h>

typedef short  s16x8 __attribute__((ext_vector_type(8)));
typedef float  f32x4 __attribute__((ext_vector_type(4)));
typedef unsigned short u16;

#define MFMA16(a, b, c) __builtin_amdgcn_mfma_f32_16x16x32_bf16((a), (b), (c), 0, 0, 0)

// ---- constants ----
#define BATCH 64
#define CIN   512
#define PP    64      // H*W
#define KCLS  100
#define H1    64
#define HID   128
#define LAT   32

// LDS strides (elements), padded so bank = 4*p pattern (2-way max, free)
#define XSTR   264    // stage-1 x chunk rows: 64 x 264  (chunk of 256 c)
#define H1STR  72     // h1T rows: 64 p x 72 (H1=64 + pad)
#define H2STR  136    // h2T rows: 64 p x 136 (HID=128 + pad)
#define H1OFF  16896  // 64*264

__device__ __forceinline__ u16 f2bf(float f) {
  unsigned u = __builtin_bit_cast(unsigned, f);
  u += 0x7fffu + ((u >> 16) & 1u);   // RNE
  return (u16)(u >> 16);
}

__device__ __forceinline__ float tanh_fast(float x) {
  // tanh(x) = 1 - 2/(1+e^{2x});  e^{2x} = 2^{x*2*log2(e)}
  float e = __builtin_amdgcn_exp2f(x * 2.8853900817779268f);
  return 1.0f - 2.0f * __builtin_amdgcn_rcpf(e + 1.0f);
}

// ---------- pre-pass: fp32 -> bf16 for the three weight tensors ----------
__global__ void convert_w(const float* __restrict__ w1, const float* __restrict__ w2,
                          const float* __restrict__ w3, u16* __restrict__ o1,
                          u16* __restrict__ o2, u16* __restrict__ o3) {
  int i = blockIdx.x * 256 + threadIdx.x;  // float4 index; grid sized exactly
  const float* src; u16* dst; int j;
  if (i < 819200)        { src = w1; dst = o1; j = i; }
  else if (i < 1024000)  { src = w2; dst = o2; j = i - 819200; }
  else                   { src = w3; dst = o3; j = i - 1024000; }
  float4 v = *(const float4*)(src + (size_t)j * 4);
  u16 o[4] = { f2bf(v.x), f2bf(v.y), f2bf(v.z), f2bf(v.w) };
  *(ulonglong1*)(dst + (size_t)j * 4) = *(ulonglong1*)o;
}

// ---------- pre-pass: x [B,C,P] fp32 -> xT [B,P,C] bf16 ----------
__global__ void transpose_x(const float* __restrict__ x, u16* __restrict__ xT) {
  __shared__ float tile[64][68];          // [c][p], pad to 68
  int b = blockIdx.x, c0 = blockIdx.y * 64;
  for (int i = threadIdx.x; i < 64 * 16; i += 256) {
    int r = i >> 4, s = i & 15;
    float4 v = *(const float4*)(x + ((size_t)b * CIN + c0 + r) * PP + s * 4);
    tile[r][s * 4 + 0] = v.x; tile[r][s * 4 + 1] = v.y;
    tile[r][s * 4 + 2] = v.z; tile[r][s * 4 + 3] = v.w;
  }
  __syncthreads();
  for (int i = threadIdx.x; i < 64 * 8; i += 256) {
    int p = i >> 3, sg = i & 7;
    u16 o[8];
    #pragma unroll
    for (int j = 0; j < 8; j++) o[j] = f2bf(tile[sg * 8 + j][p]);
    *(uint4*)(xT + ((size_t)b * PP + p) * CIN + c0 + sg * 8) = *(uint4*)o;
  }
}

// ---------- main: per-(k,b) encoder chain + distances ----------
__global__ __launch_bounds__(256, 3) void cssr_main(
    const u16* __restrict__ W1b, const u16* __restrict__ W2b, const u16* __restrict__ W3b,
    const u16* __restrict__ xT, const float* __restrict__ protos,
    const float* __restrict__ protos1, float* __restrict__ out,
    float* __restrict__ fw, float* __restrict__ f1w)
{
  __shared__ u16 sm[H1OFF + 64 * H1STR];   // stage1 x-chunk / h2T  |  h1T
  __shared__ float red[8];
  u16* smX  = sm;          // 64 x 264 (stage1), later h2T 64 x 136
  u16* smH1 = sm + H1OFF;  // 64 x 72

  const int bid  = blockIdx.x;
  const int k    = bid >> 6, b = bid & 63;
  const int tid  = threadIdx.x;
  const int w    = tid >> 6, lane = tid & 63;
  const int p16  = lane & 15, quad = lane >> 4;

  // ---------------- stage 1: h1 = tanh(W1[k] @ x[b])  [64 x 64] ----------------
  f32x4 acc1[4] = {};
  const u16* Arow = W1b + ((size_t)k * H1 + (w * 16 + p16)) * CIN + quad * 8;
  const u16* xb   = xT + (size_t)b * PP * CIN;

  for (int ch = 0; ch < 2; ch++) {
    for (int i = tid; i < 2048; i += 256) {      // 64 rows x 32 segs of 8 elems
      int p = i >> 5, s = i & 31;
      *(uint4*)(smX + p * XSTR + s * 8) = *(const uint4*)(xb + p * CIN + ch * 256 + s * 8);
    }
    __syncthreads();
    #pragma unroll
    for (int ks = 0; ks < 8; ks++) {
      s16x8 a = *(const s16x8*)(Arow + ch * 256 + ks * 32);
      #pragma unroll
      for (int nt = 0; nt < 4; nt++) {
        s16x8 bb = *(const s16x8*)(smX + (p16 + nt * 16) * XSTR + ks * 32 + quad * 8);
        acc1[nt] = MFMA16(a, bb, acc1[nt]);
      }
    }
    __syncthreads();
  }

  // tanh + store transposed h1T[p][m]; lane holds rows m = w*16+quad*4+r, col p
  #pragma unroll
  for (int nt = 0; nt < 4; nt++) {
    int p = p16 + nt * 16;
    u16 hv[4];
    #pragma unroll
    for (int r = 0; r < 4; r++) hv[r] = f2bf(tanh_fast(acc1[nt][r]));
    *(ulonglong1*)(smH1 + p * H1STR + w * 16 + quad * 4) = *(ulonglong1*)hv;
  }
  __syncthreads();

  // ---------------- stage 2: h2 = tanh(W2[k] @ h1)  [128 x 64] ----------------
  f32x4 acc2[2][4] = {};
  #pragma unroll
  for (int ks = 0; ks < 2; ks++) {
    s16x8 a0 = *(const s16x8*)(W2b + ((size_t)k * HID + (w * 32 + p16)) * H1 + ks * 32 + quad * 8);
    s16x8 a1 = *(const s16x8*)(W2b + ((size_t)k * HID + (w * 32 + 16 + p16)) * H1 + ks * 32 + quad * 8);
    #pragma unroll
    for (int nt = 0; nt < 4; nt++) {
      s16x8 bb = *(const s16x8*)(smH1 + (p16 + nt * 16) * H1STR + ks * 32 + quad * 8);
      acc2[0][nt] = MFMA16(a0, bb, acc2[0][nt]);
      acc2[1][nt] = MFMA16(a1, bb, acc2[1][nt]);
    }
  }
  // tanh + store h2T[p][m] into smX region (stage-1 reads all done: barrier above)
  #pragma unroll
  for (int mt = 0; mt < 2; mt++) {
    #pragma unroll
    for (int nt = 0; nt < 4; nt++) {
      int p = p16 + nt * 16;
      u16 hv[4];
      #pragma unroll
      for (int r = 0; r < 4; r++) hv[r] = f2bf(tanh_fast(acc2[mt][nt][r]));
      *(ulonglong1*)(smX + p * H2STR + w * 32 + mt * 16 + quad * 4) = *(ulonglong1*)hv;
    }
  }
  __syncthreads();

  // ---------------- stage 3: lt = tanh(W3[k] @ h2)  [32 x 64] ----------------
  // wave strips N: this wave owns p in [16w, 16w+16)
  f32x4 acc3[2] = {};
  const int p = p16 + w * 16;
  #pragma unroll
  for (int ks = 0; ks < 4; ks++) {
    s16x8 bb = *(const s16x8*)(smX + p * H2STR + ks * 32 + quad * 8);
    s16x8 a0 = *(const s16x8*)(W3b + ((size_t)k * LAT + p16) * HID + ks * 32 + quad * 8);
    s16x8 a1 = *(const s16x8*)(W3b + ((size_t)k * LAT + 16 + p16) * HID + ks * 32 + quad * 8);
    acc3[0] = MFMA16(a0, bb, acc3[0]);
    acc3[1] = MFMA16(a1, bb, acc3[1]);
  }

  // ---------------- distances, clip, logits, f / f1 ----------------
  float d2 = 0.f, d21 = 0.f;
  const float* pr  = protos  + (size_t)k * (LAT * PP);
  const float* pr1 = protos1 + (size_t)k * (LAT * PP);
  #pragma unroll
  for (int mt = 0; mt < 2; mt++) {
    #pragma unroll
    for (int r = 0; r < 4; r++) {
      int m = mt * 16 + quad * 4 + r;
      float lt = tanh_fast(acc3[mt][r]);
      float d  = lt - pr [m * PP + p];  d2  += d * d;
      float e  = lt - pr1[m * PP + p];  d21 += e * e;
    }
  }
  d2  += __shfl_xor(d2, 16);  d2  += __shfl_xor(d2, 32);
  d21 += __shfl_xor(d21, 16); d21 += __shfl_xor(d21, 32);
  float er  = fminf(fmaxf(d2  * -0.1f, -100.f), 100.f);
  float er1 = fminf(fmaxf(d21 * -0.1f, -100.f), 100.f);

  if (quad == 0) {
    out[(size_t)b * (KCLS * PP) + k * PP + p]          = er;
    out[409600 + (size_t)b * (KCLS * PP) + k * PP + p] = er1;
  }

  float s = er, s1 = er1;
  s += __shfl_xor(s, 1); s1 += __shfl_xor(s1, 1);
  s += __shfl_xor(s, 2); s1 += __shfl_xor(s1, 2);
  s += __shfl_xor(s, 4); s1 += __shfl_xor(s1, 4);
  s += __shfl_xor(s, 8); s1 += __shfl_xor(s1, 8);
  if (lane == 0) { red[w] = s; red[4 + w] = s1; }
  __syncthreads();
  if (tid == 0) {
    fw [k * 64 + b] = red[0] + red[1] + red[2] + red[3];
    f1w[k * 64 + b] = red[4] + red[5] + red[6] + red[7];
  }
}

// ---------- finalize: pull / push scalars ----------
__global__ void finalize(const float* __restrict__ f, const float* __restrict__ f1,
                         const int* __restrict__ ycls, float* __restrict__ out2) {
  __shared__ float rp[128], rq[128];
  int t = threadIdx.x;
  float pullk = 0.f, pushk = 0.f;
  if (t < KCLS) {
    int neq = 0, nc = 0; float s1 = 0.f, s = 0.f;
    for (int b = 0; b < BATCH; b++) {
      float fv  = f [t * 64 + b];
      float f1v = f1[t * 64 + b];
      if (ycls[b] == t)      { neq++; s1 += f1v; }
      else if (fv < 10000.f) { nc++;  s  += fv; }
    }
    if (neq > 0) pullk = s1 / (float)neq;
    if (nc  > 0) pushk = s  / (float)nc;
  }
  rp[t] = pullk; rq[t] = pushk;
  __syncthreads();
  for (int off = 64; off > 0; off >>= 1) {
    if (t < off) { rp[t] += rp[t + off]; rq[t] += rq[t + off]; }
    __syncthreads();
  }
  if (t == 0) { out2[0] = rp[0]; out2[1] = rq[0]; }
}

extern "C" void kernel_launch(void* const* d_in, const int* in_sizes, int n_in,
                              void* d_out, int out_size, void* d_ws, size_t ws_size,
                              hipStream_t stream) {
  const float* x     = (const float*)d_in[0];
  const int*   ycls  = (const int*)d_in[1];
  // d_in[2], d_in[3]: safe_margin_all / safe_distance_all — unused by reference
  const float* W1    = (const float*)d_in[4];
  const float* W2    = (const float*)d_in[5];
  const float* W3    = (const float*)d_in[6];
  const float* prot  = (const float*)d_in[7];
  const float* prot1 = (const float*)d_in[8];
  float* out = (float*)d_out;

  // workspace layout (bytes)
  char* ws = (char*)d_ws;
  u16*  xTb = (u16*)(ws);                        // 64*64*512*2   = 4,194,304
  u16*  W1b = (u16*)(ws + 4194304);              // 3,276,800*2   = 6,553,600
  u16*  W2b = (u16*)(ws + 10747904);             //   819,200*2   = 1,638,400
  u16*  W3b = (u16*)(ws + 12386304);             //   409,600*2   =   819,200
  float* fw  = (float*)(ws + 13205504);          // 6400*4
  float* f1w = (float*)(ws + 13231104);          // 6400*4

  convert_w<<<4400, 256, 0, stream>>>(W1, W2, W3, W1b, W2b, W3b);
  transpose_x<<<dim3(64, 8), 256, 0, stream>>>(x, xTb);
  cssr_main<<<KCLS * BATCH, 256, 0, stream>>>(W1b, W2b, W3b, xTb, prot, prot1, out, fw, f1w);
  finalize<<<1, 128, 0, stream>>>(fw, f1w, ycls, out + 819200);
}